// Round 1
// baseline (807.178 us; speedup 1.0000x reference)
//
#include <hip/hip_runtime.h>

using u16 = unsigned short;
typedef __bf16 bf16x8 __attribute__((ext_vector_type(8)));
typedef u16    u16x8  __attribute__((ext_vector_type(8)));
typedef u16    u16x4  __attribute__((ext_vector_type(4)));
typedef float  f32x4  __attribute__((ext_vector_type(4)));
typedef float  f32x16 __attribute__((ext_vector_type(16)));

#define DEV static __device__ __forceinline__

constexpr int NB = 4;          // batch
constexpr int NN = 20000;      // tokens
constexpr int DD = 64;         // model dim
constexpr int KK = 256;        // linformer K
constexpr int FF = 256;        // ffn dim
constexpr int ROWS = NB * NN;  // 80000 flat rows

DEV float b2f(u16 u) { union { unsigned i; float f; } c; c.i = ((unsigned)u) << 16; return c.f; }
DEV u16 f2b(float f) {
  union { float f; unsigned i; } c; c.f = f;
  unsigned i = c.i + 0x7FFFu + ((c.i >> 16) & 1u);
  return (u16)(i >> 16);
}
DEV bf16x8 ldb8(const u16* p) { return *reinterpret_cast<const bf16x8*>(p); }
DEV f32x16 mfma32(bf16x8 a, bf16x8 b, f32x16 c) { return __builtin_amdgcn_mfma_f32_32x32x16_bf16(a, b, c, 0, 0, 0); }
DEV f32x4  mfma16(bf16x8 a, bf16x8 b, f32x4 c)  { return __builtin_amdgcn_mfma_f32_16x16x32_bf16(a, b, c, 0, 0, 0); }

// Build B-fragment (32x32x16) from f32 weight matrix W[k][col], ldw = row stride.
// k0 = s*16 + hi*8 ; elements j = consecutive k rows at fixed col.
DEV bf16x8 wfrag(const float* __restrict__ W, int ldw, int k0, int col) {
  u16x8 u;
#pragma unroll
  for (int j = 0; j < 8; ++j) u[j] = f2b(W[(k0 + j) * ldw + col]);
  return __builtin_bit_cast(bf16x8, u);
}

// ---------------------------------------------------------------------------
// projK/projV [L][N][K] f32  ->  pT [L][K][N] bf16   (classic LDS transpose)
// grid: (ceil(N/64)=313, K/64=4, 4)  z: bit0=layer, bit1=proj
__global__ __launch_bounds__(256) void k_transpose(
    const float* __restrict__ projK, const float* __restrict__ projV,
    u16* __restrict__ pKT, u16* __restrict__ pVT) {
  int nt = blockIdx.x, kt = blockIdx.y, z = blockIdx.z;
  int layer = z & 1, pv = z >> 1;
  const float* src = (pv ? projV : projK) + (size_t)layer * NN * KK;
  u16* dst = (pv ? pVT : pKT) + (size_t)layer * KK * NN;
  int n0 = nt * 64, k0 = kt * 64;
  __shared__ float lds[64][65];
  int t = threadIdx.x;
  int r = t >> 4, c4 = (t & 15) * 4;
#pragma unroll
  for (int i = 0; i < 4; ++i) {
    int rr = r + i * 16;
    float4 v = make_float4(0.f, 0.f, 0.f, 0.f);
    if (n0 + rr < NN) v = *reinterpret_cast<const float4*>(&src[(size_t)(n0 + rr) * KK + k0 + c4]);
    lds[c4 + 0][rr] = v.x; lds[c4 + 1][rr] = v.y; lds[c4 + 2][rr] = v.z; lds[c4 + 3][rr] = v.w;
  }
  __syncthreads();
  int kk = t >> 2, q4 = (t & 3) * 16;
#pragma unroll
  for (int i = 0; i < 4; ++i) {
    int nn = q4 + i * 4;
    if (n0 + nn < NN) {
      u16x4 o;
#pragma unroll
      for (int m = 0; m < 4; ++m) o[m] = f2b(lds[kk][nn + m]);
      *reinterpret_cast<u16x4*>(&dst[(size_t)(k0 + kk) * NN + n0 + nn]) = o;
    }
  }
}

// ---------------------------------------------------------------------------
// x[b,n,d] = emb[n,d] * expr[b,n]  -> bf16.  grid 5000 x 256, 4 elems/thread
__global__ __launch_bounds__(256) void k_embed(
    const float* __restrict__ expr, const float* __restrict__ emb, u16* __restrict__ xb) {
  int idx4 = (blockIdx.x * 256 + threadIdx.x) * 4;
  int b = idx4 / (NN * DD);
  int rem = idx4 - b * (NN * DD);
  int n = rem >> 6, d = rem & 63;
  float4 e = *reinterpret_cast<const float4*>(&emb[(n << 6) + d]);
  float s = expr[b * NN + n];
  u16x4 o;
  o[0] = f2b(e.x * s); o[1] = f2b(e.y * s); o[2] = f2b(e.z * s); o[3] = f2b(e.w * s);
  *reinterpret_cast<u16x4*>(&xb[idx4]) = o;
}

// ---------------------------------------------------------------------------
// Row GEMM  out[M,64] = A[M,64] @ W[64,64]  (+ bias + residual + LayerNorm)
// Each wave: 64 rows x 64 cols. grid 313 x 256.
template <int EPI>
__global__ __launch_bounds__(256) void k_gemm_64_64(
    const u16* __restrict__ A, const float* __restrict__ W,
    const float* __restrict__ bias, const u16* __restrict__ res,
    const float* __restrict__ g, const float* __restrict__ be, u16* __restrict__ out) {
  int t = threadIdx.x, w = t >> 6, lane = t & 63;
  int lo = lane & 31, hi = lane >> 5;
  int unit = blockIdx.x * 4 + w;
  if (unit >= ROWS / 64) return;
  bf16x8 wf[4][2];
#pragma unroll
  for (int s = 0; s < 4; ++s)
#pragma unroll
    for (int ct = 0; ct < 2; ++ct) wf[s][ct] = wfrag(W, 64, s * 16 + hi * 8, ct * 32 + lo);
  float bia[2], gg[2], bb[2];
  if (EPI) {
#pragma unroll
    for (int ct = 0; ct < 2; ++ct) {
      bia[ct] = bias[ct * 32 + lo];
      gg[ct] = g[ct * 32 + lo];
      bb[ct] = be[ct * 32 + lo];
    }
  }
  f32x16 acc[2][2] = {};
  int r0 = unit * 64;
#pragma unroll
  for (int s = 0; s < 4; ++s) {
#pragma unroll
    for (int rt = 0; rt < 2; ++rt) {
      bf16x8 a = ldb8(&A[(size_t)(r0 + rt * 32 + lo) * 64 + s * 16 + hi * 8]);
      acc[rt][0] = mfma32(a, wf[s][0], acc[rt][0]);
      acc[rt][1] = mfma32(a, wf[s][1], acc[rt][1]);
    }
  }
#pragma unroll
  for (int rt = 0; rt < 2; ++rt) {
#pragma unroll
    for (int reg = 0; reg < 16; ++reg) {
      int row = r0 + rt * 32 + (reg & 3) + 8 * (reg >> 2) + 4 * hi;
      if (EPI == 0) {
        out[(size_t)row * 64 + lo] = f2b(acc[rt][0][reg]);
        out[(size_t)row * 64 + 32 + lo] = f2b(acc[rt][1][reg]);
      } else {
        float a0 = acc[rt][0][reg] + bia[0] + b2f(res[(size_t)row * 64 + lo]);
        float a1 = acc[rt][1][reg] + bia[1] + b2f(res[(size_t)row * 64 + 32 + lo]);
        float su = a0 + a1, sq = a0 * a0 + a1 * a1;
#pragma unroll
        for (int m = 1; m <= 16; m <<= 1) { su += __shfl_xor(su, m); sq += __shfl_xor(sq, m); }
        float mean = su * (1.f / 64.f);
        float var = sq * (1.f / 64.f) - mean * mean;
        float rstd = rsqrtf(var + 1e-5f);
        out[(size_t)row * 64 + lo] = f2b((a0 - mean) * rstd * gg[0] + bb[0]);
        out[(size_t)row * 64 + 32 + lo] = f2b((a1 - mean) * rstd * gg[1] + bb[1]);
      }
    }
  }
}

// ---------------------------------------------------------------------------
// FFN1: out[M,256] = gelu(A[M,64] @ W[64,256] + bias).  wave: 32 rows x 128 cols.
// grid 1250 x 256
__global__ __launch_bounds__(256, 2) void k_gemm_64_256(
    const u16* __restrict__ A, const float* __restrict__ W,
    const float* __restrict__ bias, u16* __restrict__ out) {
  int t = threadIdx.x, w = t >> 6, lane = t & 63;
  int lo = lane & 31, hi = lane >> 5;
  int colg = w & 1;
  int unit = blockIdx.x * 2 + (w >> 1);
  if (unit >= ROWS / 32) return;
  bf16x8 wf[4][4];
  float bia[4];
#pragma unroll
  for (int s = 0; s < 4; ++s)
#pragma unroll
    for (int ct = 0; ct < 4; ++ct) wf[s][ct] = wfrag(W, 256, s * 16 + hi * 8, colg * 128 + ct * 32 + lo);
#pragma unroll
  for (int ct = 0; ct < 4; ++ct) bia[ct] = bias[colg * 128 + ct * 32 + lo];
  f32x16 acc[4] = {};
  int r0 = unit * 32;
#pragma unroll
  for (int s = 0; s < 4; ++s) {
    bf16x8 a = ldb8(&A[(size_t)(r0 + lo) * 64 + s * 16 + hi * 8]);
#pragma unroll
    for (int ct = 0; ct < 4; ++ct) acc[ct] = mfma32(a, wf[s][ct], acc[ct]);
  }
#pragma unroll
  for (int ct = 0; ct < 4; ++ct) {
#pragma unroll
    for (int reg = 0; reg < 16; ++reg) {
      int row = r0 + (reg & 3) + 8 * (reg >> 2) + 4 * hi;
      float x = acc[ct][reg] + bia[ct];
      float gel = 0.5f * x * (1.f + erff(x * 0.7071067811865475f));
      out[(size_t)row * 256 + colg * 128 + ct * 32 + lo] = f2b(gel);
    }
  }
}

// ---------------------------------------------------------------------------
// FFN2: LN(A[M,256] @ W[256,64] + bias + res).  wave: 64 rows x 64 cols, grid 313.
__global__ __launch_bounds__(256) void k_gemm_256_64(
    const u16* __restrict__ A, const float* __restrict__ W,
    const float* __restrict__ bias, const u16* __restrict__ res,
    const float* __restrict__ g, const float* __restrict__ be,
    u16* __restrict__ outb, float* __restrict__ outf) {
  int t = threadIdx.x, w = t >> 6, lane = t & 63;
  int lo = lane & 31, hi = lane >> 5;
  int unit = blockIdx.x * 4 + w;
  if (unit >= ROWS / 64) return;
  float bia[2], gg[2], bb[2];
#pragma unroll
  for (int ct = 0; ct < 2; ++ct) {
    bia[ct] = bias[ct * 32 + lo];
    gg[ct] = g[ct * 32 + lo];
    bb[ct] = be[ct * 32 + lo];
  }
  f32x16 acc[2][2] = {};
  int r0 = unit * 64;
#pragma unroll
  for (int s = 0; s < 16; ++s) {
    bf16x8 w0 = wfrag(W, 64, s * 16 + hi * 8, lo);
    bf16x8 w1 = wfrag(W, 64, s * 16 + hi * 8, 32 + lo);
#pragma unroll
    for (int rt = 0; rt < 2; ++rt) {
      bf16x8 a = ldb8(&A[(size_t)(r0 + rt * 32 + lo) * 256 + s * 16 + hi * 8]);
      acc[rt][0] = mfma32(a, w0, acc[rt][0]);
      acc[rt][1] = mfma32(a, w1, acc[rt][1]);
    }
  }
#pragma unroll
  for (int rt = 0; rt < 2; ++rt) {
#pragma unroll
    for (int reg = 0; reg < 16; ++reg) {
      int row = r0 + rt * 32 + (reg & 3) + 8 * (reg >> 2) + 4 * hi;
      float a0 = acc[rt][0][reg] + bia[0] + b2f(res[(size_t)row * 64 + lo]);
      float a1 = acc[rt][1][reg] + bia[1] + b2f(res[(size_t)row * 64 + 32 + lo]);
      float su = a0 + a1, sq = a0 * a0 + a1 * a1;
#pragma unroll
      for (int m = 1; m <= 16; m <<= 1) { su += __shfl_xor(su, m); sq += __shfl_xor(sq, m); }
      float mean = su * (1.f / 64.f);
      float var = sq * (1.f / 64.f) - mean * mean;
      float rstd = rsqrtf(var + 1e-5f);
      float o0 = (a0 - mean) * rstd * gg[0] + bb[0];
      float o1 = (a1 - mean) * rstd * gg[1] + bb[1];
      if (outb) {
        outb[(size_t)row * 64 + lo] = f2b(o0);
        outb[(size_t)row * 64 + 32 + lo] = f2b(o1);
      }
      if (outf) {
        outf[(size_t)row * 64 + lo] = o0;
        outf[(size_t)row * 64 + 32 + lo] = o1;
      }
    }
  }
}

// ---------------------------------------------------------------------------
// Linformer projection partials: part[proj][b][chunk][256][64] += pT[k][n]*x[b][n][d]
// grid (20 chunks, B, 4: bit1=proj bit0=khalf), wave = 32 k-rows x 64 d
__global__ __launch_bounds__(256) void k_proj(
    const u16* __restrict__ xin, const u16* __restrict__ pKT_l, const u16* __restrict__ pVT_l,
    float* __restrict__ part) {
  int c = blockIdx.x, b = blockIdx.y, z = blockIdx.z;
  int proj = z >> 1, khalf = z & 1;
  const u16* Apt = proj ? pVT_l : pKT_l;
  int t = threadIdx.x, w = t >> 6, lane = t & 63;
  int lo = lane & 31, hi = lane >> 5;
  int k0 = khalf * 128 + w * 32;
  int n0 = c * 1024;
  int rem = NN - n0;
  int steps = (rem < 1024 ? rem : 1024) >> 4;
  const u16* xb = xin + (size_t)b * NN * 64;
  f32x16 acc[2] = {};
  for (int s = 0; s < steps; ++s) {
    int nbase = n0 + s * 16;
    bf16x8 a = ldb8(&Apt[(size_t)(k0 + lo) * NN + nbase + hi * 8]);
    u16x8 u0, u1;
#pragma unroll
    for (int j = 0; j < 8; ++j) {
      const u16* xr = &xb[(size_t)(nbase + hi * 8 + j) * 64];
      u0[j] = xr[lo];
      u1[j] = xr[32 + lo];
    }
    acc[0] = mfma32(a, __builtin_bit_cast(bf16x8, u0), acc[0]);
    acc[1] = mfma32(a, __builtin_bit_cast(bf16x8, u1), acc[1]);
  }
  float* dst = part + ((size_t)(proj * NB + b) * 20 + c) * (KK * DD);
#pragma unroll
  for (int ct = 0; ct < 2; ++ct)
#pragma unroll
    for (int reg = 0; reg < 16; ++reg) {
      int kk = k0 + (reg & 3) + 8 * (reg >> 2) + 4 * hi;
      dst[kk * 64 + ct * 32 + lo] = acc[ct][reg];
    }
}

// ---------------------------------------------------------------------------
// Reduce partials, apply Wk/Wv.  proj0 -> k [b][256][64] bf16 ; proj1 -> vT [b][64][256] bf16
// grid (8 ktiles, B, 2)
__global__ __launch_bounds__(256) void k_p2(
    const float* __restrict__ part, const float* __restrict__ Wk_l, const float* __restrict__ Wv_l,
    u16* __restrict__ kbuf, u16* __restrict__ vT) {
  int kt = blockIdx.x, b = blockIdx.y, proj = blockIdx.z;
  int k0 = kt * 32;
  const float* W = proj ? Wv_l : Wk_l;
  __shared__ float low[32][64];
  int t = threadIdx.x, w = t >> 6, lane = t & 63;
  const float* src = part + (size_t)(proj * NB + b) * 20 * (KK * DD);
#pragma unroll
  for (int i = 0; i < 8; ++i) {
    int k = i * 4 + w, d = lane;
    float s = 0.f;
    for (int c = 0; c < 20; ++c) s += src[(size_t)c * (KK * DD) + (k0 + k) * 64 + d];
    low[k][d] = s;
  }
  __syncthreads();
#pragma unroll
  for (int i = 0; i < 8; ++i) {
    int k = i * 4 + w, d = lane;
    float acc = 0.f;
    for (int e = 0; e < 64; ++e) acc += low[k][e] * W[e * 64 + d];
    u16 o = f2b(acc);
    if (proj == 0)
      kbuf[((size_t)b * KK + k0 + k) * 64 + d] = o;
    else
      vT[((size_t)b * 64 + d) * KK + k0 + k] = o;
  }
}

// ---------------------------------------------------------------------------
// Fused Linformer attention.  grid (157, B), block = 4 waves, wave = 32 rows.
// QK: 32x32x16 (inner=DH=16), softmax in regs, normalized P -> swizzled LDS,
// PV: 16x16x32 reading vT straight from global.
__global__ __launch_bounds__(256, 2) void k_attn(
    const u16* __restrict__ q, const u16* __restrict__ kbuf, const u16* __restrict__ vT,
    u16* __restrict__ ao) {
  __shared__ u16 P[4][32 * 256];  // 64 KB, per-wave private 16 KB tiles
  int t = threadIdx.x, w = t >> 6, lane = t & 63;
  int lo = lane & 31, hi = lane >> 5;
  int b = blockIdx.y;
  int n0w = blockIdx.x * 128 + w * 32;
  if (n0w >= NN) return;
  u16* Pw = P[w];
  const u16* qb = q + (size_t)b * NN * 64;
  const u16* kb = kbuf + (size_t)b * KK * 64;
  const u16* vtb = vT + (size_t)b * 64 * KK;
  u16* aob = ao + (size_t)b * NN * 64;
  const float C = 0.25f * 1.4426950408889634f;  // SCALE * log2(e)
  for (int h = 0; h < 4; ++h) {
    bf16x8 aq = ldb8(&qb[(size_t)(n0w + lo) * 64 + h * 16 + hi * 8]);
    f32x16 sc[8];
#pragma unroll
    for (int kt = 0; kt < 8; ++kt) {
      bf16x8 bk = ldb8(&kb[(size_t)(kt * 32 + lo) * 64 + h * 16 + hi * 8]);
      f32x16 z = {};
      sc[kt] = mfma32(aq, bk, z);
    }
    float mx[16], sm[16], inv[16];
#pragma unroll
    for (int r = 0; r < 16; ++r) {
      float m = sc[0][r];
#pragma unroll
      for (int kt = 1; kt < 8; ++kt) m = fmaxf(m, sc[kt][r]);
#pragma unroll
      for (int msk = 1; msk <= 16; msk <<= 1) m = fmaxf(m, __shfl_xor(m, msk));
      mx[r] = m;
      sm[r] = 0.f;
    }
#pragma unroll
    for (int kt = 0; kt < 8; ++kt)
#pragma unroll
      for (int r = 0; r < 16; ++r) {
        float e = exp2f((sc[kt][r] - mx[r]) * C);
        sc[kt][r] = e;
        sm[r] += e;
      }
#pragma unroll
    for (int r = 0; r < 16; ++r) {
      float s = sm[r];
#pragma unroll
      for (int msk = 1; msk <= 16; msk <<= 1) s += __shfl_xor(s, msk);
      inv[r] = 1.f / s;
    }
#pragma unroll
    for (int kt = 0; kt < 8; ++kt)
#pragma unroll
      for (int r = 0; r < 16; ++r) {
        int row = (r & 3) + 8 * (r >> 2) + 4 * hi;
        int key = kt * 32 + lo;
        int off = row * 256 + (((key >> 3) ^ (row & 7)) << 3) + (key & 7);
        Pw[off] = f2b(sc[kt][r] * inv[r]);
      }
    // PV
    int quad = lane >> 4, l16 = lane & 15;
#pragma unroll
    for (int rt = 0; rt < 2; ++rt) {
      f32x4 o = {};
      int row = rt * 16 + l16;
#pragma unroll
      for (int s = 0; s < 8; ++s) {
        int gsw = (s * 4 + quad) ^ (row & 7);
        bf16x8 ap = *reinterpret_cast<const bf16x8*>(&Pw[row * 256 + (gsw << 3)]);
        bf16x8 bv = ldb8(&vtb[(size_t)(h * 16 + l16) * KK + s * 32 + quad * 8]);
        o = mfma16(ap, bv, o);
      }
#pragma unroll
      for (int c2 = 0; c2 < 4; ++c2) {
        int rr = rt * 16 + quad * 4 + c2;
        aob[(size_t)(n0w + rr) * 64 + h * 16 + l16] = f2b(o[c2]);
      }
    }
  }
}

// ---------------------------------------------------------------------------
extern "C" void kernel_launch(void* const* d_in, const int* in_sizes, int n_in,
                              void* d_out, int out_size, void* d_ws, size_t ws_size,
                              hipStream_t stream) {
  const float* expr = (const float*)d_in[0];
  const float* emb  = (const float*)d_in[1];
  const float* Wq   = (const float*)d_in[2];
  const float* Wk   = (const float*)d_in[3];
  const float* Wv   = (const float*)d_in[4];
  const float* projK = (const float*)d_in[5];
  const float* projV = (const float*)d_in[6];
  const float* Wo   = (const float*)d_in[7];
  const float* bo   = (const float*)d_in[8];
  const float* g1   = (const float*)d_in[9];
  const float* be1  = (const float*)d_in[10];
  const float* W1   = (const float*)d_in[11];
  const float* bf1  = (const float*)d_in[12];
  const float* W2   = (const float*)d_in[13];
  const float* bf2  = (const float*)d_in[14];
  const float* g2   = (const float*)d_in[15];
  const float* be2  = (const float*)d_in[16];
  float* out = (float*)d_out;
  char* ws = (char*)d_ws;

  // workspace layout (bytes)
  u16* xb0 = (u16*)(ws + 0);                 // 10,240,000
  u16* xb1 = (u16*)(ws + 10240000);          // 10,240,000
  u16* xb2 = (u16*)(ws + 20480000);          // 10,240,000
  u16* qb  = (u16*)(ws + 30720000);          // 10,240,000
  u16* aob = (u16*)(ws + 40960000);          // 10,240,000
  u16* hb  = (u16*)(ws + 51200000);          // 40,960,000
  u16* pKT = (u16*)(ws + 92160000);          // 20,480,000 (2 layers)
  u16* pVT = (u16*)(ws + 112640000);         // 20,480,000
  float* part = (float*)(ws + 133120000);    // 10,485,760
  u16* kB  = (u16*)(ws + 143605760);         // 131,072
  u16* vTB = (u16*)(ws + 143736832);         // 131,072   (end ~143.9 MB)

  k_transpose<<<dim3(313, 4, 4), 256, 0, stream>>>(projK, projV, pKT, pVT);
  k_embed<<<5000, 256, 0, stream>>>(expr, emb, xb0);

  const u16* xin = xb0;
  for (int l = 0; l < 2; ++l) {
    k_gemm_64_64<0><<<313, 256, 0, stream>>>(xin, Wq + l * 4096, nullptr, nullptr, nullptr, nullptr, qb);
    k_proj<<<dim3(20, NB, 4), 256, 0, stream>>>(xin, pKT + (size_t)l * KK * NN, pVT + (size_t)l * KK * NN, part);
    k_p2<<<dim3(8, NB, 2), 256, 0, stream>>>(part, Wk + l * 4096, Wv + l * 4096, kB, vTB);
    k_attn<<<dim3(157, NB), 256, 0, stream>>>(qb, kB, vTB, aob);
    k_gemm_64_64<1><<<313, 256, 0, stream>>>(aob, Wo + l * 4096, bo + l * 64, xin, g1 + l * 64, be1 + l * 64, xb1);
    k_gemm_64_256<<<1250, 256, 0, stream>>>(xb1, W1 + l * 16384, bf1 + l * 256, hb);
    k_gemm_256_64<<<313, 256, 0, stream>>>(hb, W2 + l * 16384, bf2 + l * 64, xb1,
                                           g2 + l * 64, be2 + l * 64,
                                           l == 0 ? xb2 : nullptr, l == 1 ? out : nullptr);
    xin = xb2;
  }
}

// Round 2
// 581.755 us; speedup vs baseline: 1.3875x; 1.3875x over previous
//
#include <hip/hip_runtime.h>

using u16 = unsigned short;
typedef __bf16 bf16x8 __attribute__((ext_vector_type(8)));
typedef u16    u16x8  __attribute__((ext_vector_type(8)));
typedef u16    u16x4  __attribute__((ext_vector_type(4)));
typedef float  f32x4  __attribute__((ext_vector_type(4)));
typedef float  f32x16 __attribute__((ext_vector_type(16)));

#define DEV static __device__ __forceinline__

constexpr int NB = 4;          // batch
constexpr int NN = 20000;      // tokens
constexpr int DD = 64;         // model dim
constexpr int KK = 256;        // linformer K
constexpr int ROWS = NB * NN;  // 80000 flat rows

DEV float b2f(u16 u) { union { unsigned i; float f; } c; c.i = ((unsigned)u) << 16; return c.f; }
DEV u16 f2b(float f) {
  union { float f; unsigned i; } c; c.f = f;
  unsigned i = c.i + 0x7FFFu + ((c.i >> 16) & 1u);
  return (u16)(i >> 16);
}
DEV bf16x8 ldb8(const u16* p) { return *reinterpret_cast<const bf16x8*>(p); }
DEV f32x16 mfma32(bf16x8 a, bf16x8 b, f32x16 c) { return __builtin_amdgcn_mfma_f32_32x32x16_bf16(a, b, c, 0, 0, 0); }

// Build B-fragment (32x32x16) from f32 weight matrix W[k][col], ldw = row stride.
DEV bf16x8 wfrag(const float* __restrict__ W, int ldw, int k0, int col) {
  u16x8 u;
#pragma unroll
  for (int j = 0; j < 8; ++j) u[j] = f2b(W[(k0 + j) * ldw + col]);
  return __builtin_bit_cast(bf16x8, u);
}

// ---------------------------------------------------------------------------
// projK/projV [L][N][K] f32  ->  pT [L][K][N] bf16   (classic LDS transpose)
// grid: (313, K/64=4, 4)  z: bit0=layer, bit1=proj
__global__ __launch_bounds__(256) void k_transpose(
    const float* __restrict__ projK, const float* __restrict__ projV,
    u16* __restrict__ pKT, u16* __restrict__ pVT) {
  int nt = blockIdx.x, kt = blockIdx.y, z = blockIdx.z;
  int layer = z & 1, pv = z >> 1;
  const float* src = (pv ? projV : projK) + (size_t)layer * NN * KK;
  u16* dst = (pv ? pVT : pKT) + (size_t)layer * KK * NN;
  int n0 = nt * 64, k0 = kt * 64;
  __shared__ float lds[64][65];
  int t = threadIdx.x;
  int r = t >> 4, c4 = (t & 15) * 4;
#pragma unroll
  for (int i = 0; i < 4; ++i) {
    int rr = r + i * 16;
    float4 v = make_float4(0.f, 0.f, 0.f, 0.f);
    if (n0 + rr < NN) v = *reinterpret_cast<const float4*>(&src[(size_t)(n0 + rr) * KK + k0 + c4]);
    lds[c4 + 0][rr] = v.x; lds[c4 + 1][rr] = v.y; lds[c4 + 2][rr] = v.z; lds[c4 + 3][rr] = v.w;
  }
  __syncthreads();
  int kk = t >> 2, q4 = (t & 3) * 16;
#pragma unroll
  for (int i = 0; i < 4; ++i) {
    int nn = q4 + i * 4;
    if (n0 + nn < NN) {
      u16x4 o;
#pragma unroll
      for (int m = 0; m < 4; ++m) o[m] = f2b(lds[kk][nn + m]);
      *reinterpret_cast<u16x4*>(&dst[(size_t)(k0 + kk) * NN + n0 + nn]) = o;
    }
  }
}

// ---------------------------------------------------------------------------
// x [b][n][64] bf16 -> xT [b][64][NN] bf16.  grid (313, NB)
__global__ __launch_bounds__(256) void k_xt(const u16* __restrict__ x, u16* __restrict__ xT) {
  int nt = blockIdx.x, b = blockIdx.y;
  int n0 = nt * 64;
  __shared__ u16 lds[64][72];
  int t = threadIdx.x;
  int r = t >> 4, c4 = (t & 15) * 4;
  const u16* xb = x + (size_t)b * NN * 64;
#pragma unroll
  for (int i = 0; i < 4; ++i) {
    int rr = r + i * 16;
    u16x4 v = {};
    if (n0 + rr < NN) v = *reinterpret_cast<const u16x4*>(&xb[(size_t)(n0 + rr) * 64 + c4]);
    lds[c4 + 0][rr] = v[0]; lds[c4 + 1][rr] = v[1];
    lds[c4 + 2][rr] = v[2]; lds[c4 + 3][rr] = v[3];
  }
  __syncthreads();
  int d = t >> 2, q4 = (t & 3) * 16;
  u16* xo = xT + (size_t)b * 64 * NN;
#pragma unroll
  for (int i = 0; i < 4; ++i) {
    int nn = q4 + i * 4;
    if (n0 + nn + 3 < NN) {
      u16x4 o;
#pragma unroll
      for (int m = 0; m < 4; ++m) o[m] = lds[d][nn + m];
      *reinterpret_cast<u16x4*>(&xo[(size_t)d * NN + n0 + nn]) = o;
    } else {
#pragma unroll
      for (int m = 0; m < 4; ++m)
        if (n0 + nn + m < NN) xo[(size_t)d * NN + n0 + nn + m] = lds[d][nn + m];
    }
  }
}

// ---------------------------------------------------------------------------
// x[b,n,d] = emb[n,d] * expr[b,n]  -> bf16.  grid 5000 x 256
__global__ __launch_bounds__(256) void k_embed(
    const float* __restrict__ expr, const float* __restrict__ emb, u16* __restrict__ xb) {
  int idx4 = (blockIdx.x * 256 + threadIdx.x) * 4;
  int b = idx4 / (NN * DD);
  int rem = idx4 - b * (NN * DD);
  int n = rem >> 6, d = rem & 63;
  float4 e = *reinterpret_cast<const float4*>(&emb[(n << 6) + d]);
  float s = expr[b * NN + n];
  u16x4 o;
  o[0] = f2b(e.x * s); o[1] = f2b(e.y * s); o[2] = f2b(e.z * s); o[3] = f2b(e.w * s);
  *reinterpret_cast<u16x4*>(&xb[idx4]) = o;
}

// ---------------------------------------------------------------------------
// Row GEMM  out[M,64] = A[M,64] @ W[64,64]  (+ bias + residual + LayerNorm)
template <int EPI>
__global__ __launch_bounds__(256) void k_gemm_64_64(
    const u16* __restrict__ A, const float* __restrict__ W,
    const float* __restrict__ bias, const u16* __restrict__ res,
    const float* __restrict__ g, const float* __restrict__ be, u16* __restrict__ out) {
  int t = threadIdx.x, w = t >> 6, lane = t & 63;
  int lo = lane & 31, hi = lane >> 5;
  int unit = blockIdx.x * 4 + w;
  if (unit >= ROWS / 64) return;
  bf16x8 wf[4][2];
#pragma unroll
  for (int s = 0; s < 4; ++s)
#pragma unroll
    for (int ct = 0; ct < 2; ++ct) wf[s][ct] = wfrag(W, 64, s * 16 + hi * 8, ct * 32 + lo);
  float bia[2], gg[2], bb[2];
  if (EPI) {
#pragma unroll
    for (int ct = 0; ct < 2; ++ct) {
      bia[ct] = bias[ct * 32 + lo];
      gg[ct] = g[ct * 32 + lo];
      bb[ct] = be[ct * 32 + lo];
    }
  }
  f32x16 acc[2][2] = {};
  int r0 = unit * 64;
#pragma unroll
  for (int s = 0; s < 4; ++s) {
#pragma unroll
    for (int rt = 0; rt < 2; ++rt) {
      bf16x8 a = ldb8(&A[(size_t)(r0 + rt * 32 + lo) * 64 + s * 16 + hi * 8]);
      acc[rt][0] = mfma32(a, wf[s][0], acc[rt][0]);
      acc[rt][1] = mfma32(a, wf[s][1], acc[rt][1]);
    }
  }
#pragma unroll
  for (int rt = 0; rt < 2; ++rt) {
#pragma unroll
    for (int reg = 0; reg < 16; ++reg) {
      int row = r0 + rt * 32 + (reg & 3) + 8 * (reg >> 2) + 4 * hi;
      if (EPI == 0) {
        out[(size_t)row * 64 + lo] = f2b(acc[rt][0][reg]);
        out[(size_t)row * 64 + 32 + lo] = f2b(acc[rt][1][reg]);
      } else {
        float a0 = acc[rt][0][reg] + bia[0] + b2f(res[(size_t)row * 64 + lo]);
        float a1 = acc[rt][1][reg] + bia[1] + b2f(res[(size_t)row * 64 + 32 + lo]);
        float su = a0 + a1, sq = a0 * a0 + a1 * a1;
#pragma unroll
        for (int m = 1; m <= 16; m <<= 1) { su += __shfl_xor(su, m); sq += __shfl_xor(sq, m); }
        float mean = su * (1.f / 64.f);
        float var = sq * (1.f / 64.f) - mean * mean;
        float rstd = rsqrtf(var + 1e-5f);
        out[(size_t)row * 64 + lo] = f2b((a0 - mean) * rstd * gg[0] + bb[0]);
        out[(size_t)row * 64 + 32 + lo] = f2b((a1 - mean) * rstd * gg[1] + bb[1]);
      }
    }
  }
}

// ---------------------------------------------------------------------------
// FFN1: out[M,256] = gelu(A[M,64] @ W[64,256] + bias)
__global__ __launch_bounds__(256, 2) void k_gemm_64_256(
    const u16* __restrict__ A, const float* __restrict__ W,
    const float* __restrict__ bias, u16* __restrict__ out) {
  int t = threadIdx.x, w = t >> 6, lane = t & 63;
  int lo = lane & 31, hi = lane >> 5;
  int colg = w & 1;
  int unit = blockIdx.x * 2 + (w >> 1);
  if (unit >= ROWS / 32) return;
  bf16x8 wf[4][4];
  float bia[4];
#pragma unroll
  for (int s = 0; s < 4; ++s)
#pragma unroll
    for (int ct = 0; ct < 4; ++ct) wf[s][ct] = wfrag(W, 256, s * 16 + hi * 8, colg * 128 + ct * 32 + lo);
#pragma unroll
  for (int ct = 0; ct < 4; ++ct) bia[ct] = bias[colg * 128 + ct * 32 + lo];
  f32x16 acc[4] = {};
  int r0 = unit * 32;
#pragma unroll
  for (int s = 0; s < 4; ++s) {
    bf16x8 a = ldb8(&A[(size_t)(r0 + lo) * 64 + s * 16 + hi * 8]);
#pragma unroll
    for (int ct = 0; ct < 4; ++ct) acc[ct] = mfma32(a, wf[s][ct], acc[ct]);
  }
#pragma unroll
  for (int ct = 0; ct < 4; ++ct) {
#pragma unroll
    for (int reg = 0; reg < 16; ++reg) {
      int row = r0 + (reg & 3) + 8 * (reg >> 2) + 4 * hi;
      float x = acc[ct][reg] + bia[ct];
      float gel = 0.5f * x * (1.f + erff(x * 0.7071067811865475f));
      out[(size_t)row * 256 + colg * 128 + ct * 32 + lo] = f2b(gel);
    }
  }
}

// ---------------------------------------------------------------------------
// FFN2: LN(A[M,256] @ W[256,64] + bias + res)
__global__ __launch_bounds__(256) void k_gemm_256_64(
    const u16* __restrict__ A, const float* __restrict__ W,
    const float* __restrict__ bias, const u16* __restrict__ res,
    const float* __restrict__ g, const float* __restrict__ be,
    u16* __restrict__ outb, float* __restrict__ outf) {
  int t = threadIdx.x, w = t >> 6, lane = t & 63;
  int lo = lane & 31, hi = lane >> 5;
  int unit = blockIdx.x * 4 + w;
  if (unit >= ROWS / 64) return;
  float bia[2], gg[2], bb[2];
#pragma unroll
  for (int ct = 0; ct < 2; ++ct) {
    bia[ct] = bias[ct * 32 + lo];
    gg[ct] = g[ct * 32 + lo];
    bb[ct] = be[ct * 32 + lo];
  }
  f32x16 acc[2][2] = {};
  int r0 = unit * 64;
#pragma unroll
  for (int s = 0; s < 16; ++s) {
    bf16x8 w0 = wfrag(W, 64, s * 16 + hi * 8, lo);
    bf16x8 w1 = wfrag(W, 64, s * 16 + hi * 8, 32 + lo);
#pragma unroll
    for (int rt = 0; rt < 2; ++rt) {
      bf16x8 a = ldb8(&A[(size_t)(r0 + rt * 32 + lo) * 256 + s * 16 + hi * 8]);
      acc[rt][0] = mfma32(a, w0, acc[rt][0]);
      acc[rt][1] = mfma32(a, w1, acc[rt][1]);
    }
  }
#pragma unroll
  for (int rt = 0; rt < 2; ++rt) {
#pragma unroll
    for (int reg = 0; reg < 16; ++reg) {
      int row = r0 + rt * 32 + (reg & 3) + 8 * (reg >> 2) + 4 * hi;
      float a0 = acc[rt][0][reg] + bia[0] + b2f(res[(size_t)row * 64 + lo]);
      float a1 = acc[rt][1][reg] + bia[1] + b2f(res[(size_t)row * 64 + 32 + lo]);
      float su = a0 + a1, sq = a0 * a0 + a1 * a1;
#pragma unroll
      for (int m = 1; m <= 16; m <<= 1) { su += __shfl_xor(su, m); sq += __shfl_xor(sq, m); }
      float mean = su * (1.f / 64.f);
      float var = sq * (1.f / 64.f) - mean * mean;
      float rstd = rsqrtf(var + 1e-5f);
      float o0 = (a0 - mean) * rstd * gg[0] + bb[0];
      float o1 = (a1 - mean) * rstd * gg[1] + bb[1];
      if (outb) {
        outb[(size_t)row * 64 + lo] = f2b(o0);
        outb[(size_t)row * 64 + 32 + lo] = f2b(o1);
      }
      if (outf) {
        outf[(size_t)row * 64 + lo] = o0;
        outf[(size_t)row * 64 + 32 + lo] = o1;
      }
    }
  }
}

// ---------------------------------------------------------------------------
// Linformer projection partials (xT-based, both fragments contiguous b128):
// part[proj][b][c][64 d][256 k] = sum_n xT[d][n] * pT[k][n] over chunk c.
// grid (40 chunks, NB, 2 proj), block 256 = 4 waves.
// wave: d-half = w&1 (32 rows), k-half = w>>1 (128 cols = 4 accs)
__global__ __launch_bounds__(256) void k_proj(
    const u16* __restrict__ xT, const u16* __restrict__ pKT_l, const u16* __restrict__ pVT_l,
    float* __restrict__ part) {
  int c = blockIdx.x, b = blockIdx.y, proj = blockIdx.z;
  const u16* P = proj ? pVT_l : pKT_l;
  int t = threadIdx.x, w = t >> 6, lane = t & 63;
  int lo = lane & 31, hi = lane >> 5;
  int d0 = (w & 1) * 32;
  int kbase = (w >> 1) * 128;
  int n0 = c * 512;
  int rem = NN - n0;
  int steps = (rem < 512 ? rem : 512) >> 4;
  const u16* xr = xT + ((size_t)b * 64 + d0 + lo) * NN;
  f32x16 acc[4] = {};
  for (int s = 0; s < steps; ++s) {
    int nb = n0 + s * 16 + hi * 8;
    bf16x8 a = ldb8(&xr[nb]);
#pragma unroll
    for (int gI = 0; gI < 4; ++gI) {
      bf16x8 bfr = ldb8(&P[(size_t)(kbase + gI * 32 + lo) * NN + nb]);
      acc[gI] = mfma32(a, bfr, acc[gI]);
    }
  }
  float* dst = part + ((size_t)(proj * NB + b) * 40 + c) * (64 * 256);
#pragma unroll
  for (int gI = 0; gI < 4; ++gI)
#pragma unroll
    for (int r = 0; r < 16; ++r) {
      int d = d0 + (r & 3) + 8 * (r >> 2) + 4 * hi;
      dst[d * 256 + kbase + gI * 32 + lo] = acc[gI][r];
    }
}

// ---------------------------------------------------------------------------
// Reduce partials (40 chunks) + apply Wk/Wv.
// part layout [proj][b][c][64 e][256 k]. grid (8 kslices, NB, 2)
// proj0 -> kbuf [b][256 k][64 d]; proj1 -> vT [b][64 d][256 k]
__global__ __launch_bounds__(256) void k_p2(
    const float* __restrict__ part, const float* __restrict__ Wk_l, const float* __restrict__ Wv_l,
    u16* __restrict__ kbuf, u16* __restrict__ vT) {
  int ks = blockIdx.x, b = blockIdx.y, proj = blockIdx.z;
  int k0 = ks * 32;
  const float* W = proj ? Wv_l : Wk_l;
  __shared__ float low[64][33];
  int t = threadIdx.x;
  const float* src = part + (size_t)(proj * NB + b) * 40 * (64 * 256);
#pragma unroll
  for (int i = 0; i < 8; ++i) {
    int e = (t >> 5) + i * 8, k = t & 31;
    float ssum = 0.f;
    for (int cc = 0; cc < 40; ++cc) ssum += src[(size_t)cc * (64 * 256) + e * 256 + k0 + k];
    low[e][k] = ssum;
  }
  __syncthreads();
#pragma unroll
  for (int i = 0; i < 8; ++i) {
    int kk = (t >> 6) + i * 4, d = t & 63;
    float a = 0.f;
#pragma unroll
    for (int e = 0; e < 64; ++e) a += low[e][kk] * W[e * 64 + d];
    u16 o = f2b(a);
    if (proj == 0)
      kbuf[((size_t)b * KK + k0 + kk) * 64 + d] = o;
    else
      vT[((size_t)b * 64 + d) * KK + k0 + kk] = o;
  }
}

// ---------------------------------------------------------------------------
// Fused Linformer attention, register-only (S^T = K.Q^T trick, no LDS).
// grid (157, 4 heads, NB), block 256 = 4 waves; wave = 32 queries x 1 head.
__global__ __launch_bounds__(256) void k_attn(
    const u16* __restrict__ q, const u16* __restrict__ kbuf, const u16* __restrict__ vT,
    u16* __restrict__ ao) {
  int t = threadIdx.x, w = t >> 6, lane = t & 63;
  int lo = lane & 31, hi = lane >> 5;
  int h = blockIdx.y, b = blockIdx.z;
  int n0w = blockIdx.x * 128 + w * 32;
  if (n0w >= NN) return;
  const u16* qb = q + (size_t)b * NN * 64;
  const u16* kb = kbuf + (size_t)b * KK * 64 + h * 16;
  const u16* vtb = vT + (size_t)b * 64 * KK + (size_t)(h * 16 + (lane & 15)) * KK;
  u16* aob = ao + (size_t)b * NN * 64;
  const float C = 0.25f * 1.4426950408889634f;  // SCALE * log2(e)
  // Q fragment: B-operand of S^T = K.Q^T  (lane = query col, elems = d)
  bf16x8 qf = ldb8(&qb[(size_t)(n0w + lo) * 64 + h * 16 + hi * 8]);
  f32x16 acc = {};
  float ssum = 0.f;
#pragma unroll
  for (int kt = 0; kt < 8; ++kt) {
    bf16x8 kf = ldb8(&kb[(size_t)(kt * 32 + lo) * 64 + hi * 8]);
    f32x16 z = {};
    f32x16 s = mfma32(kf, qf, z);  // S^T tile: col = query(lo), rows = 32 keys
#pragma unroll
    for (int r = 0; r < 16; ++r) { s[r] = exp2f(s[r] * C); ssum += s[r]; }
    // repack C-layout rows -> B-operand k-layout via xor-32 shuffles, 2 chunks of 16 keys
#pragma unroll
    for (int c = 0; c < 2; ++c) {
      float px[8];
#pragma unroll
      for (int j = 0; j < 8; ++j) px[j] = __shfl_xor(s[c * 8 + j], 32);
      u16x8 bu;
#pragma unroll
      for (int j = 0; j < 4; ++j) {
        bu[j] = f2b(hi ? px[4 + j] : s[c * 8 + j]);       // k = hi*8 + j
        bu[4 + j] = f2b(hi ? s[c * 8 + 4 + j] : px[j]);   // k = hi*8 + 4 + j
      }
      bf16x8 af = ldb8(&vtb[kt * 32 + c * 16 + hi * 8]);  // V^T rows (d), dup for lanes 16..31
      acc = mfma32(af, __builtin_bit_cast(bf16x8, bu), acc);
    }
  }
  ssum += __shfl_xor(ssum, 32);
  float inv = 1.f / ssum;
  float o[8], ox[8];
#pragma unroll
  for (int r = 0; r < 8; ++r) o[r] = acc[r] * inv;  // valid d rows 0..15 live in regs 0..7
#pragma unroll
  for (int r = 0; r < 8; ++r) ox[r] = __shfl_xor(o[r], 32);
  u16x8 st;
#pragma unroll
  for (int j = 0; j < 4; ++j) {
    st[j] = f2b(hi ? ox[4 + j] : o[j]);
    st[4 + j] = f2b(hi ? o[4 + j] : ox[j]);
  }
  *reinterpret_cast<u16x8*>(&aob[(size_t)(n0w + lo) * 64 + h * 16 + hi * 8]) = st;
}

// ---------------------------------------------------------------------------
extern "C" void kernel_launch(void* const* d_in, const int* in_sizes, int n_in,
                              void* d_out, int out_size, void* d_ws, size_t ws_size,
                              hipStream_t stream) {
  const float* expr = (const float*)d_in[0];
  const float* emb  = (const float*)d_in[1];
  const float* Wq   = (const float*)d_in[2];
  const float* Wk   = (const float*)d_in[3];
  const float* Wv   = (const float*)d_in[4];
  const float* projK = (const float*)d_in[5];
  const float* projV = (const float*)d_in[6];
  const float* Wo   = (const float*)d_in[7];
  const float* bo   = (const float*)d_in[8];
  const float* g1   = (const float*)d_in[9];
  const float* be1  = (const float*)d_in[10];
  const float* W1   = (const float*)d_in[11];
  const float* bf1  = (const float*)d_in[12];
  const float* W2   = (const float*)d_in[13];
  const float* bf2  = (const float*)d_in[14];
  const float* g2   = (const float*)d_in[15];
  const float* be2  = (const float*)d_in[16];
  float* out = (float*)d_out;
  char* ws = (char*)d_ws;

  // workspace layout (bytes)
  u16* xb0 = (u16*)(ws + 0);                 // 10,240,000
  u16* xb1 = (u16*)(ws + 10240000);          // 10,240,000
  u16* xb2 = (u16*)(ws + 20480000);          // 10,240,000
  u16* qb  = (u16*)(ws + 30720000);          // 10,240,000
  u16* aob = (u16*)(ws + 40960000);          // 10,240,000
  u16* hb  = (u16*)(ws + 51200000);          // 40,960,000  (FFN hidden)
  float* part = (float*)(ws + 51200000);     // 20,971,520  -- aliases hb (disjoint lifetimes)
  u16* pKT = (u16*)(ws + 92160000);          // 20,480,000 (2 layers)
  u16* pVT = (u16*)(ws + 112640000);         // 20,480,000
  u16* xTb = (u16*)(ws + 133120000);         // 10,240,000
  u16* kB  = (u16*)(ws + 143360000);         // 131,072
  u16* vTB = (u16*)(ws + 143491072);         // 131,072   (end ~143.6 MB)

  k_transpose<<<dim3(313, 4, 4), 256, 0, stream>>>(projK, projV, pKT, pVT);
  k_embed<<<5000, 256, 0, stream>>>(expr, emb, xb0);

  const u16* xin = xb0;
  for (int l = 0; l < 2; ++l) {
    k_gemm_64_64<0><<<313, 256, 0, stream>>>(xin, Wq + l * 4096, nullptr, nullptr, nullptr, nullptr, qb);
    k_xt<<<dim3(313, NB), 256, 0, stream>>>(xin, xTb);
    k_proj<<<dim3(40, NB, 2), 256, 0, stream>>>(xTb, pKT + (size_t)l * KK * NN, pVT + (size_t)l * KK * NN, part);
    k_p2<<<dim3(8, NB, 2), 256, 0, stream>>>(part, Wk + l * 4096, Wv + l * 4096, kB, vTB);
    k_attn<<<dim3(157, 4, NB), 256, 0, stream>>>(qb, kB, vTB, aob);
    k_gemm_64_64<1><<<313, 256, 0, stream>>>(aob, Wo + l * 4096, bo + l * 64, xin, g1 + l * 64, be1 + l * 64, xb1);
    k_gemm_64_256<<<1250, 256, 0, stream>>>(xb1, W1 + l * 16384, bf1 + l * 256, hb);
    k_gemm_256_64<<<313, 256, 0, stream>>>(hb, W2 + l * 16384, bf2 + l * 64, xb1,
                                           g2 + l * 64, be2 + l * 64,
                                           l == 0 ? xb2 : nullptr, l == 1 ? out : nullptr);
    xin = xb2;
  }
}

// Round 3
// 490.391 us; speedup vs baseline: 1.6460x; 1.1863x over previous
//
#include <hip/hip_runtime.h>

using u16 = unsigned short;
typedef __bf16 bf16x8 __attribute__((ext_vector_type(8)));
typedef u16    u16x8  __attribute__((ext_vector_type(8)));
typedef u16    u16x4  __attribute__((ext_vector_type(4)));
typedef float  f32x4  __attribute__((ext_vector_type(4)));
typedef float  f32x16 __attribute__((ext_vector_type(16)));

#define DEV static __device__ __forceinline__

constexpr int NB = 4;          // batch
constexpr int NN = 20000;      // tokens
constexpr int DD = 64;         // model dim
constexpr int KK = 256;        // linformer K
constexpr int ROWS = NB * NN;  // 80000 flat rows

DEV float b2f(u16 u) { union { unsigned i; float f; } c; c.i = ((unsigned)u) << 16; return c.f; }
DEV u16 f2b(float f) {
  union { float f; unsigned i; } c; c.f = f;
  unsigned i = c.i + 0x7FFFu + ((c.i >> 16) & 1u);
  return (u16)(i >> 16);
}
DEV bf16x8 ldb8(const u16* p) { return *reinterpret_cast<const bf16x8*>(p); }
DEV f32x16 mfma32(bf16x8 a, bf16x8 b, f32x16 c) { return __builtin_amdgcn_mfma_f32_32x32x16_bf16(a, b, c, 0, 0, 0); }

// ---------------------------------------------------------------------------
// Weight pre-conversion: f32 -> bf16 in MFMA B-fragment order.
// frag element (s, ct, lane, j) = W[(s*16 + (lane>>5)*8 + j)*Dout + ct*32 + (lane&31)]
// wb offsets (elems): Wq: l*4096 | Wo: 8192+l*4096 | W1: 16384+l*16384 | W2: 49152+l*16384
__global__ __launch_bounds__(256) void k_wconv(
    const float* __restrict__ Wq, const float* __restrict__ Wo,
    const float* __restrict__ W1, const float* __restrict__ W2, u16* __restrict__ wb) {
  int m = blockIdx.y, l = blockIdx.z;
  const float* src; u16* dst; int Dout, S, CT;
  if (m == 0)      { src = Wq + l * 4096;  dst = wb + l * 4096;          Dout = 64;  S = 4;  CT = 2; }
  else if (m == 1) { src = Wo + l * 4096;  dst = wb + 8192 + l * 4096;   Dout = 64;  S = 4;  CT = 2; }
  else if (m == 2) { src = W1 + l * 16384; dst = wb + 16384 + l * 16384; Dout = 256; S = 4;  CT = 8; }
  else             { src = W2 + l * 16384; dst = wb + 49152 + l * 16384; Dout = 64;  S = 16; CT = 2; }
  int slot = blockIdx.x * 256 + threadIdx.x;
  if (slot >= S * CT * 64) return;
  int s = slot / (CT * 64), rem = slot % (CT * 64);
  int ct = rem >> 6, lane = rem & 63;
  int hi = lane >> 5, lo = lane & 31;
  u16x8 o;
#pragma unroll
  for (int j = 0; j < 8; ++j) o[j] = f2b(src[(s * 16 + hi * 8 + j) * Dout + ct * 32 + lo]);
  *reinterpret_cast<u16x8*>(&dst[slot * 8]) = o;
}

// ---------------------------------------------------------------------------
// projK/projV [L][N][K] f32 -> pT [L][K][N] bf16.
// Full-line u16x8 stores: 8 lanes cover 128B contiguous per output row.
__global__ __launch_bounds__(256) void k_transpose(
    const float* __restrict__ projK, const float* __restrict__ projV,
    u16* __restrict__ pKT, u16* __restrict__ pVT) {
  int nt = blockIdx.x, kt = blockIdx.y, z = blockIdx.z;
  int layer = z & 1, pv = z >> 1;
  const float* src = (pv ? projV : projK) + (size_t)layer * NN * KK;
  u16* dst = (pv ? pVT : pKT) + (size_t)layer * KK * NN;
  int n0 = nt * 64, k0 = kt * 64;
  __shared__ float lds[64][65];  // lds[k][n]
  int t = threadIdx.x;
  int r = t >> 4, c4 = (t & 15) * 4;
#pragma unroll
  for (int i = 0; i < 4; ++i) {
    int rr = r + i * 16;
    float4 v = make_float4(0.f, 0.f, 0.f, 0.f);
    if (n0 + rr < NN) v = *reinterpret_cast<const float4*>(&src[(size_t)(n0 + rr) * KK + k0 + c4]);
    lds[c4 + 0][rr] = v.x; lds[c4 + 1][rr] = v.y; lds[c4 + 2][rr] = v.z; lds[c4 + 3][rr] = v.w;
  }
  __syncthreads();
  int kr = t >> 3, nb = (t & 7) * 8;
#pragma unroll
  for (int p = 0; p < 2; ++p) {
    int k = kr + p * 32;
    if (n0 + nb < NN) {  // NN%64==32, nb multiple of 8 -> tile chunks are all-or-nothing
      u16x8 o;
#pragma unroll
      for (int j = 0; j < 8; ++j) o[j] = f2b(lds[k][nb + j]);
      *reinterpret_cast<u16x8*>(&dst[(size_t)(k0 + k) * NN + n0 + nb]) = o;
    }
  }
}

// ---------------------------------------------------------------------------
// x [b][n][64] bf16 -> xT [b][64][NN] bf16, full-line u16x8 stores.
__global__ __launch_bounds__(256) void k_xt(const u16* __restrict__ x, u16* __restrict__ xT) {
  int nt = blockIdx.x, b = blockIdx.y;
  int n0 = nt * 64;
  __shared__ u16 lds[64][70];  // lds[d][n], pitch 70 u16 = 35 dwords (odd) -> ~2-way banks
  int t = threadIdx.x;
  int r = t >> 4, c4 = (t & 15) * 4;
  const u16* xb = x + (size_t)b * NN * 64;
#pragma unroll
  for (int i = 0; i < 4; ++i) {
    int rr = r + i * 16;
    u16x4 v = {};
    if (n0 + rr < NN) v = *reinterpret_cast<const u16x4*>(&xb[(size_t)(n0 + rr) * 64 + c4]);
    lds[c4 + 0][rr] = v[0]; lds[c4 + 1][rr] = v[1];
    lds[c4 + 2][rr] = v[2]; lds[c4 + 3][rr] = v[3];
  }
  __syncthreads();
  int dr = t >> 3, nb = (t & 7) * 8;
  u16* xo = xT + (size_t)b * 64 * NN;
#pragma unroll
  for (int p = 0; p < 2; ++p) {
    int d = dr + p * 32;
    if (n0 + nb < NN) {
      u16x8 o;
#pragma unroll
      for (int j = 0; j < 8; ++j) o[j] = lds[d][nb + j];
      *reinterpret_cast<u16x8*>(&xo[(size_t)d * NN + n0 + nb]) = o;
    }
  }
}

// ---------------------------------------------------------------------------
// x[b,n,d] = emb[n,d] * expr[b,n] -> bf16.  8 elems/thread, grid 2500.
__global__ __launch_bounds__(256) void k_embed(
    const float* __restrict__ expr, const float* __restrict__ emb, u16* __restrict__ xb) {
  int idx8 = (blockIdx.x * 256 + threadIdx.x) * 8;
  int b = idx8 / (NN * DD);
  int rem = idx8 - b * (NN * DD);
  int n = rem >> 6, d = rem & 63;
  float4 e0 = *reinterpret_cast<const float4*>(&emb[(n << 6) + d]);
  float4 e1 = *reinterpret_cast<const float4*>(&emb[(n << 6) + d + 4]);
  float s = expr[b * NN + n];
  u16x8 o;
  o[0] = f2b(e0.x * s); o[1] = f2b(e0.y * s); o[2] = f2b(e0.z * s); o[3] = f2b(e0.w * s);
  o[4] = f2b(e1.x * s); o[5] = f2b(e1.y * s); o[6] = f2b(e1.z * s); o[7] = f2b(e1.w * s);
  *reinterpret_cast<u16x8*>(&xb[idx8]) = o;
}

// ---------------------------------------------------------------------------
// Row GEMM  out[M,64] = A[M,64] @ W[64,64]  (+ bias + residual + LayerNorm)
// WB = bf16 fragment-order weights (CT=2).
template <int EPI>
__global__ __launch_bounds__(256) void k_gemm_64_64(
    const u16* __restrict__ A, const u16* __restrict__ WB,
    const float* __restrict__ bias, const u16* __restrict__ res,
    const float* __restrict__ g, const float* __restrict__ be, u16* __restrict__ out) {
  int t = threadIdx.x, w = t >> 6, lane = t & 63;
  int lo = lane & 31, hi = lane >> 5;
  int unit = blockIdx.x * 4 + w;
  if (unit >= ROWS / 64) return;
  bf16x8 wf[4][2];
#pragma unroll
  for (int s = 0; s < 4; ++s)
#pragma unroll
    for (int ct = 0; ct < 2; ++ct) wf[s][ct] = ldb8(&WB[((s * 2 + ct) * 64 + lane) * 8]);
  float bia[2], gg[2], bb[2];
  if (EPI) {
#pragma unroll
    for (int ct = 0; ct < 2; ++ct) {
      bia[ct] = bias[ct * 32 + lo];
      gg[ct] = g[ct * 32 + lo];
      bb[ct] = be[ct * 32 + lo];
    }
  }
  f32x16 acc[2][2] = {};
  int r0 = unit * 64;
#pragma unroll
  for (int s = 0; s < 4; ++s) {
#pragma unroll
    for (int rt = 0; rt < 2; ++rt) {
      bf16x8 a = ldb8(&A[(size_t)(r0 + rt * 32 + lo) * 64 + s * 16 + hi * 8]);
      acc[rt][0] = mfma32(a, wf[s][0], acc[rt][0]);
      acc[rt][1] = mfma32(a, wf[s][1], acc[rt][1]);
    }
  }
#pragma unroll
  for (int rt = 0; rt < 2; ++rt) {
#pragma unroll
    for (int reg = 0; reg < 16; ++reg) {
      int row = r0 + rt * 32 + (reg & 3) + 8 * (reg >> 2) + 4 * hi;
      if (EPI == 0) {
        out[(size_t)row * 64 + lo] = f2b(acc[rt][0][reg]);
        out[(size_t)row * 64 + 32 + lo] = f2b(acc[rt][1][reg]);
      } else {
        float a0 = acc[rt][0][reg] + bia[0] + b2f(res[(size_t)row * 64 + lo]);
        float a1 = acc[rt][1][reg] + bia[1] + b2f(res[(size_t)row * 64 + 32 + lo]);
        float su = a0 + a1, sq = a0 * a0 + a1 * a1;
#pragma unroll
        for (int m = 1; m <= 16; m <<= 1) { su += __shfl_xor(su, m); sq += __shfl_xor(sq, m); }
        float mean = su * (1.f / 64.f);
        float var = sq * (1.f / 64.f) - mean * mean;
        float rstd = rsqrtf(var + 1e-5f);
        out[(size_t)row * 64 + lo] = f2b((a0 - mean) * rstd * gg[0] + bb[0]);
        out[(size_t)row * 64 + 32 + lo] = f2b((a1 - mean) * rstd * gg[1] + bb[1]);
      }
    }
  }
}

// ---------------------------------------------------------------------------
// FFN1: out[M,256] = gelu(A[M,64] @ W1[64,256] + bias).  WB fragment-order (CT=8).
__global__ __launch_bounds__(256, 2) void k_gemm_64_256(
    const u16* __restrict__ A, const u16* __restrict__ WB,
    const float* __restrict__ bias, u16* __restrict__ out) {
  int t = threadIdx.x, w = t >> 6, lane = t & 63;
  int lo = lane & 31, hi = lane >> 5;
  int colg = w & 1;
  int unit = blockIdx.x * 2 + (w >> 1);
  if (unit >= ROWS / 32) return;
  bf16x8 wf[4][4];
  float bia[4];
#pragma unroll
  for (int s = 0; s < 4; ++s)
#pragma unroll
    for (int ct = 0; ct < 4; ++ct) wf[s][ct] = ldb8(&WB[((s * 8 + colg * 4 + ct) * 64 + lane) * 8]);
#pragma unroll
  for (int ct = 0; ct < 4; ++ct) bia[ct] = bias[colg * 128 + ct * 32 + lo];
  f32x16 acc[4] = {};
  int r0 = unit * 32;
#pragma unroll
  for (int s = 0; s < 4; ++s) {
    bf16x8 a = ldb8(&A[(size_t)(r0 + lo) * 64 + s * 16 + hi * 8]);
#pragma unroll
    for (int ct = 0; ct < 4; ++ct) acc[ct] = mfma32(a, wf[s][ct], acc[ct]);
  }
#pragma unroll
  for (int ct = 0; ct < 4; ++ct) {
#pragma unroll
    for (int reg = 0; reg < 16; ++reg) {
      int row = r0 + (reg & 3) + 8 * (reg >> 2) + 4 * hi;
      float x = acc[ct][reg] + bia[ct];
      float gel = 0.5f * x * (1.f + erff(x * 0.7071067811865475f));
      out[(size_t)row * 256 + colg * 128 + ct * 32 + lo] = f2b(gel);
    }
  }
}

// ---------------------------------------------------------------------------
// FFN2: LN(A[M,256] @ W2[256,64] + bias + res).  WB fragment-order (S=16, CT=2).
__global__ __launch_bounds__(256) void k_gemm_256_64(
    const u16* __restrict__ A, const u16* __restrict__ WB,
    const float* __restrict__ bias, const u16* __restrict__ res,
    const float* __restrict__ g, const float* __restrict__ be,
    u16* __restrict__ outb, float* __restrict__ outf) {
  int t = threadIdx.x, w = t >> 6, lane = t & 63;
  int lo = lane & 31, hi = lane >> 5;
  int unit = blockIdx.x * 4 + w;
  if (unit >= ROWS / 64) return;
  float bia[2], gg[2], bb[2];
#pragma unroll
  for (int ct = 0; ct < 2; ++ct) {
    bia[ct] = bias[ct * 32 + lo];
    gg[ct] = g[ct * 32 + lo];
    bb[ct] = be[ct * 32 + lo];
  }
  f32x16 acc[2][2] = {};
  int r0 = unit * 64;
#pragma unroll
  for (int s = 0; s < 16; ++s) {
    bf16x8 w0 = ldb8(&WB[((s * 2 + 0) * 64 + lane) * 8]);
    bf16x8 w1 = ldb8(&WB[((s * 2 + 1) * 64 + lane) * 8]);
#pragma unroll
    for (int rt = 0; rt < 2; ++rt) {
      bf16x8 a = ldb8(&A[(size_t)(r0 + rt * 32 + lo) * 256 + s * 16 + hi * 8]);
      acc[rt][0] = mfma32(a, w0, acc[rt][0]);
      acc[rt][1] = mfma32(a, w1, acc[rt][1]);
    }
  }
#pragma unroll
  for (int rt = 0; rt < 2; ++rt) {
#pragma unroll
    for (int reg = 0; reg < 16; ++reg) {
      int row = r0 + rt * 32 + (reg & 3) + 8 * (reg >> 2) + 4 * hi;
      float a0 = acc[rt][0][reg] + bia[0] + b2f(res[(size_t)row * 64 + lo]);
      float a1 = acc[rt][1][reg] + bia[1] + b2f(res[(size_t)row * 64 + 32 + lo]);
      float su = a0 + a1, sq = a0 * a0 + a1 * a1;
#pragma unroll
      for (int m = 1; m <= 16; m <<= 1) { su += __shfl_xor(su, m); sq += __shfl_xor(sq, m); }
      float mean = su * (1.f / 64.f);
      float var = sq * (1.f / 64.f) - mean * mean;
      float rstd = rsqrtf(var + 1e-5f);
      float o0 = (a0 - mean) * rstd * gg[0] + bb[0];
      float o1 = (a1 - mean) * rstd * gg[1] + bb[1];
      if (outb) {
        outb[(size_t)row * 64 + lo] = f2b(o0);
        outb[(size_t)row * 64 + 32 + lo] = f2b(o1);
      }
      if (outf) {
        outf[(size_t)row * 64 + lo] = o0;
        outf[(size_t)row * 64 + 32 + lo] = o1;
      }
    }
  }
}

// ---------------------------------------------------------------------------
// Linformer projection partials: part[proj][b][c][64 d][256 k] = sum_n xT[d][n]*pT[k][n]
// grid (40 chunks, NB, 2 proj), 4 waves: (d-half, k-half)
__global__ __launch_bounds__(256) void k_proj(
    const u16* __restrict__ xT, const u16* __restrict__ pKT_l, const u16* __restrict__ pVT_l,
    float* __restrict__ part) {
  int c = blockIdx.x, b = blockIdx.y, proj = blockIdx.z;
  const u16* P = proj ? pVT_l : pKT_l;
  int t = threadIdx.x, w = t >> 6, lane = t & 63;
  int lo = lane & 31, hi = lane >> 5;
  int d0 = (w & 1) * 32;
  int kbase = (w >> 1) * 128;
  int n0 = c * 512;
  int rem = NN - n0;
  int steps = (rem < 512 ? rem : 512) >> 4;
  const u16* xr = xT + ((size_t)b * 64 + d0 + lo) * NN;
  f32x16 acc[4] = {};
  for (int s = 0; s < steps; ++s) {
    int nb = n0 + s * 16 + hi * 8;
    bf16x8 a = ldb8(&xr[nb]);
#pragma unroll
    for (int gI = 0; gI < 4; ++gI) {
      bf16x8 bfr = ldb8(&P[(size_t)(kbase + gI * 32 + lo) * NN + nb]);
      acc[gI] = mfma32(a, bfr, acc[gI]);
    }
  }
  float* dst = part + ((size_t)(proj * NB + b) * 40 + c) * (64 * 256);
#pragma unroll
  for (int gI = 0; gI < 4; ++gI)
#pragma unroll
    for (int r = 0; r < 16; ++r) {
      int d = d0 + (r & 3) + 8 * (r >> 2) + 4 * hi;
      dst[d * 256 + kbase + gI * 32 + lo] = acc[gI][r];
    }
}

// ---------------------------------------------------------------------------
// Reduce 40 chunk-partials + apply Wk/Wv.  grid (32 kslices of 8, NB, 2) = 256 blocks.
// proj0 -> kbuf [b][256 k][64 d]; proj1 -> vT [b][64 d][256 k]
__global__ __launch_bounds__(256) void k_p2(
    const float* __restrict__ part, const float* __restrict__ Wk_l, const float* __restrict__ Wv_l,
    u16* __restrict__ kbuf, u16* __restrict__ vT) {
  int ks = blockIdx.x, b = blockIdx.y, proj = blockIdx.z;
  int k0 = ks * 8;
  const float* W = proj ? Wv_l : Wk_l;
  __shared__ float low[64][8];
  int t = threadIdx.x;
  const float* src = part + (size_t)(proj * NB + b) * 40 * (64 * 256);
#pragma unroll
  for (int i = 0; i < 2; ++i) {
    int idx = i * 256 + t;
    int e = idx >> 3, k = idx & 7;
    float s = 0.f;
    for (int cc = 0; cc < 40; ++cc) s += src[(size_t)cc * (64 * 256) + e * 256 + k0 + k];
    low[e][k] = s;
  }
  __syncthreads();
#pragma unroll
  for (int i = 0; i < 2; ++i) {
    int idx = i * 256 + t;
    int d = idx & 63, kk = idx >> 6;
    float a = 0.f;
#pragma unroll
    for (int e = 0; e < 64; ++e) a += low[e][kk] * W[e * 64 + d];
    u16 o = f2b(a);
    if (proj == 0)
      kbuf[((size_t)b * KK + k0 + kk) * 64 + d] = o;
    else
      vT[((size_t)b * 64 + d) * KK + k0 + kk] = o;
  }
}

// ---------------------------------------------------------------------------
// Fused Linformer attention, register-only (S^T = K.Q^T), no LDS.
// grid (157, 4 heads, NB), block 256 = 4 waves; wave = 32 queries x 1 head.
__global__ __launch_bounds__(256) void k_attn(
    const u16* __restrict__ q, const u16* __restrict__ kbuf, const u16* __restrict__ vT,
    u16* __restrict__ ao) {
  int t = threadIdx.x, w = t >> 6, lane = t & 63;
  int lo = lane & 31, hi = lane >> 5;
  int h = blockIdx.y, b = blockIdx.z;
  int n0w = blockIdx.x * 128 + w * 32;
  if (n0w >= NN) return;
  const u16* qb = q + (size_t)b * NN * 64;
  const u16* kb = kbuf + (size_t)b * KK * 64 + h * 16;
  const u16* vtb = vT + (size_t)b * 64 * KK + (size_t)(h * 16 + (lane & 15)) * KK;
  u16* aob = ao + (size_t)b * NN * 64;
  const float C = 0.25f * 1.4426950408889634f;  // SCALE * log2(e)
  bf16x8 qf = ldb8(&qb[(size_t)(n0w + lo) * 64 + h * 16 + hi * 8]);
  f32x16 acc = {};
  float ssum = 0.f;
#pragma unroll
  for (int kt = 0; kt < 8; ++kt) {
    bf16x8 kf = ldb8(&kb[(size_t)(kt * 32 + lo) * 64 + hi * 8]);
    f32x16 z = {};
    f32x16 s = mfma32(kf, qf, z);  // S^T tile: col = query(lo), rows = 32 keys
#pragma unroll
    for (int r = 0; r < 16; ++r) { s[r] = exp2f(s[r] * C); ssum += s[r]; }
#pragma unroll
    for (int c = 0; c < 2; ++c) {
      float px[8];
#pragma unroll
      for (int j = 0; j < 8; ++j) px[j] = __shfl_xor(s[c * 8 + j], 32);
      u16x8 bu;
#pragma unroll
      for (int j = 0; j < 4; ++j) {
        bu[j] = f2b(hi ? px[4 + j] : s[c * 8 + j]);
        bu[4 + j] = f2b(hi ? s[c * 8 + 4 + j] : px[j]);
      }
      bf16x8 af = ldb8(&vtb[kt * 32 + c * 16 + hi * 8]);
      acc = mfma32(af, __builtin_bit_cast(bf16x8, bu), acc);
    }
  }
  ssum += __shfl_xor(ssum, 32);
  float inv = 1.f / ssum;
  float o[8], ox[8];
#pragma unroll
  for (int r = 0; r < 8; ++r) o[r] = acc[r] * inv;
#pragma unroll
  for (int r = 0; r < 8; ++r) ox[r] = __shfl_xor(o[r], 32);
  u16x8 st;
#pragma unroll
  for (int j = 0; j < 4; ++j) {
    st[j] = f2b(hi ? ox[4 + j] : o[j]);
    st[4 + j] = f2b(hi ? o[4 + j] : ox[j]);
  }
  *reinterpret_cast<u16x8*>(&aob[(size_t)(n0w + lo) * 64 + h * 16 + hi * 8]) = st;
}

// ---------------------------------------------------------------------------
extern "C" void kernel_launch(void* const* d_in, const int* in_sizes, int n_in,
                              void* d_out, int out_size, void* d_ws, size_t ws_size,
                              hipStream_t stream) {
  const float* expr = (const float*)d_in[0];
  const float* emb  = (const float*)d_in[1];
  const float* Wq   = (const float*)d_in[2];
  const float* Wk   = (const float*)d_in[3];
  const float* Wv   = (const float*)d_in[4];
  const float* projK = (const float*)d_in[5];
  const float* projV = (const float*)d_in[6];
  const float* Wo   = (const float*)d_in[7];
  const float* bo   = (const float*)d_in[8];
  const float* g1   = (const float*)d_in[9];
  const float* be1  = (const float*)d_in[10];
  const float* W1   = (const float*)d_in[11];
  const float* bf1  = (const float*)d_in[12];
  const float* W2   = (const float*)d_in[13];
  const float* bf2  = (const float*)d_in[14];
  const float* g2   = (const float*)d_in[15];
  const float* be2  = (const float*)d_in[16];
  float* out = (float*)d_out;
  char* ws = (char*)d_ws;

  // workspace layout (bytes)
  u16* xb0 = (u16*)(ws + 0);                 // 10,240,000
  u16* xb1 = (u16*)(ws + 10240000);          // 10,240,000
  u16* xb2 = (u16*)(ws + 20480000);          // 10,240,000
  u16* qb  = (u16*)(ws + 30720000);          // 10,240,000
  u16* aob = (u16*)(ws + 40960000);          // 10,240,000
  u16* hb  = (u16*)(ws + 51200000);          // 40,960,000  (FFN hidden)
  float* part = (float*)(ws + 51200000);     // 20,971,520  -- aliases hb (disjoint lifetimes)
  u16* pKT = (u16*)(ws + 92160000);          // 20,480,000 (2 layers)
  u16* pVT = (u16*)(ws + 112640000);         // 20,480,000
  u16* xTb = (u16*)(ws + 133120000);         // 10,240,000
  u16* kB  = (u16*)(ws + 143360000);         // 131,072
  u16* vTB = (u16*)(ws + 143491072);         // 131,072
  u16* wb  = (u16*)(ws + 143622144);         // 163,840   (end ~143.8 MB)

  k_wconv<<<dim3(8, 4, 2), 256, 0, stream>>>(Wq, Wo, W1, W2, wb);
  k_transpose<<<dim3(313, 4, 4), 256, 0, stream>>>(projK, projV, pKT, pVT);
  k_embed<<<2500, 256, 0, stream>>>(expr, emb, xb0);

  const u16* xin = xb0;
  for (int l = 0; l < 2; ++l) {
    const u16* wbq = wb + l * 4096;
    const u16* wbo = wb + 8192 + l * 4096;
    const u16* wb1 = wb + 16384 + l * 16384;
    const u16* wb2 = wb + 49152 + l * 16384;
    k_gemm_64_64<0><<<313, 256, 0, stream>>>(xin, wbq, nullptr, nullptr, nullptr, nullptr, qb);
    k_xt<<<dim3(313, NB), 256, 0, stream>>>(xin, xTb);
    k_proj<<<dim3(40, NB, 2), 256, 0, stream>>>(xTb, pKT + (size_t)l * KK * NN, pVT + (size_t)l * KK * NN, part);
    k_p2<<<dim3(32, NB, 2), 256, 0, stream>>>(part, Wk + l * 4096, Wv + l * 4096, kB, vTB);
    k_attn<<<dim3(157, 4, NB), 256, 0, stream>>>(qb, kB, vTB, aob);
    k_gemm_64_64<1><<<313, 256, 0, stream>>>(aob, wbo, bo + l * 64, xin, g1 + l * 64, be1 + l * 64, xb1);
    k_gemm_64_256<<<1250, 256, 0, stream>>>(xb1, wb1, bf1 + l * 256, hb);
    k_gemm_256_64<<<313, 256, 0, stream>>>(hb, wb2, bf2 + l * 64, xb1,
                                           g2 + l * 64, be2 + l * 64,
                                           l == 0 ? xb2 : nullptr, l == 1 ? out : nullptr);
    xin = xb2;
  }
}